// Round 1
// baseline (251.438 us; speedup 1.0000x reference)
//
#include <hip/hip_runtime.h>
#include <hip/hip_cooperative_groups.h>
#include <hip/hip_bf16.h>
#include <cstddef>
#include <cstdint>

namespace cg = cooperative_groups;

#define T_LEN 32
#define E_LEN 256
#define BATCH 16
#define DIM 512
#define HID 512
#define WROW 1024  // HID + DIM

#define TWO_LOG2E 2.8853900817779268f  // 2*log2(e)
#define LOG2E 1.4426950408889634f

typedef __attribute__((ext_vector_type(8))) short bf16x8;
typedef __attribute__((ext_vector_type(4))) float f32x4;

__device__ inline bf16x8 cvt8(float4 a, float4 b) {
    union { bf16x8 v; __hip_bfloat16 h[8]; } u;
    u.h[0] = __float2bfloat16(a.x); u.h[1] = __float2bfloat16(a.y);
    u.h[2] = __float2bfloat16(a.z); u.h[3] = __float2bfloat16(a.w);
    u.h[4] = __float2bfloat16(b.x); u.h[5] = __float2bfloat16(b.y);
    u.h[6] = __float2bfloat16(b.z); u.h[7] = __float2bfloat16(b.w);
    return u.v;
}

#define GPAD 8
#define GLDR (64 + GPAD)   // 72 halfwords per LDS row

// ---------------------------------------------------------------------------
// Phase A: fused projection GEMM (NT), f32 in -> bf16 MFMA -> exp2 -> out.
// u < 64:   EPT(f32)  = 2^(TWO_LOG2E*(topic @ W[:,:D]^T + b_attn))  (M=512)
// u >= 64:  EPE(bf16) = 2^(TWO_LOG2E*(expo @ W[:,D:]^T))            (M=4096)
// Tile 64x64, BK=64, 256 threads, register-double-buffered global loads.
// ---------------------------------------------------------------------------
__device__ __forceinline__ void gemm_body(
    int u, int tid, __hip_bfloat16* As, __hip_bfloat16* Bs,
    const float* __restrict__ topic, const float* __restrict__ expo,
    const float* __restrict__ W, const float* __restrict__ battn,
    float* __restrict__ EPT, __hip_bfloat16* __restrict__ EPE) {
    const int by = u >> 3;            // 0..71
    const int n0 = (u & 7) * 64;
    const float* A; const float* Wp; int m0;
    const bool isT = (by < 8);
    if (isT) { A = topic; Wp = W;       m0 = by * 64; }
    else     { A = expo;  Wp = W + DIM; m0 = (by - 8) * 64; }
    const int w = tid >> 6;
    const int lane = tid & 63;
    const int l15 = lane & 15;
    const int g = lane >> 4;
    const int srow = tid >> 2;   // 0..63
    const int sc = tid & 3;      // halfword chunks at sc*8 and sc*8+32

    f32x4 acc[4];
    const f32x4 z = {0.f, 0.f, 0.f, 0.f};
#pragma unroll
    for (int nt = 0; nt < 4; ++nt) acc[nt] = z;

    const float* ga = A + (size_t)(m0 + srow) * 512 + sc * 8;
    const float* gb = Wp + (size_t)(n0 + srow) * WROW + sc * 8;

    float4 a0 = *(const float4*)(ga);
    float4 a1 = *(const float4*)(ga + 4);
    float4 a2 = *(const float4*)(ga + 32);
    float4 a3 = *(const float4*)(ga + 36);
    float4 b0 = *(const float4*)(gb);
    float4 b1 = *(const float4*)(gb + 4);
    float4 b2 = *(const float4*)(gb + 32);
    float4 b3 = *(const float4*)(gb + 36);

    for (int kk = 0; kk < 8; ++kk) {
        bf16x8 av0 = cvt8(a0, a1), av1 = cvt8(a2, a3);
        bf16x8 bv0 = cvt8(b0, b1), bv1 = cvt8(b2, b3);
        if (kk < 7) {  // prefetch next K-chunk while this one computes
            ga += 64; gb += 64;
            a0 = *(const float4*)(ga);
            a1 = *(const float4*)(ga + 4);
            a2 = *(const float4*)(ga + 32);
            a3 = *(const float4*)(ga + 36);
            b0 = *(const float4*)(gb);
            b1 = *(const float4*)(gb + 4);
            b2 = *(const float4*)(gb + 32);
            b3 = *(const float4*)(gb + 36);
        }
        __syncthreads();
        *(bf16x8*)&As[srow * GLDR + sc * 8] = av0;
        *(bf16x8*)&As[srow * GLDR + sc * 8 + 32] = av1;
        *(bf16x8*)&Bs[srow * GLDR + sc * 8] = bv0;
        *(bf16x8*)&Bs[srow * GLDR + sc * 8 + 32] = bv1;
        __syncthreads();
#pragma unroll
        for (int s = 0; s < 2; ++s) {
            bf16x8 af = *(const bf16x8*)&As[(w * 16 + l15) * GLDR + (s * 4 + g) * 8];
#pragma unroll
            for (int nt = 0; nt < 4; ++nt) {
                bf16x8 bf = *(const bf16x8*)&Bs[(nt * 16 + l15) * GLDR + (s * 4 + g) * 8];
                acc[nt] = __builtin_amdgcn_mfma_f32_16x16x32_bf16(af, bf, acc[nt], 0, 0, 0);
            }
        }
    }
    if (isT) {
#pragma unroll
        for (int nt = 0; nt < 4; ++nt) {
            int n = n0 + nt * 16 + l15;
            float bv = battn[n];
#pragma unroll
            for (int r = 0; r < 4; ++r) {
                int m = m0 + w * 16 + g * 4 + r;
                EPT[(size_t)m * 512 + n] =
                    __builtin_amdgcn_exp2f((acc[nt][r] + bv) * TWO_LOG2E);
            }
        }
    } else {
#pragma unroll
        for (int nt = 0; nt < 4; ++nt) {
            int n = n0 + nt * 16 + l15;
#pragma unroll
            for (int r = 0; r < 4; ++r) {
                int m = m0 + w * 16 + g * 4 + r;
                EPE[(size_t)m * 512 + n] = __float2bfloat16(
                    __builtin_amdgcn_exp2f(acc[nt][r] * TWO_LOG2E));
            }
        }
    }
}

// ---------------------------------------------------------------------------
// Phase B: energies -> P = exp(energy - const(sum v + b_score)); masked->1e-30.
// 4-way reciprocal combining: sum_{j=0..3} sv_j/(1+a_j) = N/D with
//   d01=(1+a0)(1+a1)=fma(a1,u0,u0), n01=fma(sv0,a1,fma(sv1,a0,sv0+sv1)),
//   D=d01*d23, N=fma(n01,d23,n23*d01)  -> 15 full-rate VALU + 1 rcp per quad
// (was 8 fma + 4 rcp). a_j >= 0 always (product of exps), so D in [1, ~e^28];
// no cancellation, no overflow.
// Wave: 4 e's x 8 t's; unit = (b, 8 t's, 16 e's); 1024 units.
// ---------------------------------------------------------------------------
__device__ __forceinline__ void energies_body(
    int u, int tid,
    const float* __restrict__ EPT, const __hip_bfloat16* __restrict__ EPE,
    const float* __restrict__ v, const int* __restrict__ mask,
    float* __restrict__ P) {
    const int b = u & 15;
    const int tg = (u >> 4) & 3;   // t = tg*8 + i
    const int ech = u >> 6;        // e base = ech*16
    const int lane = tid & 63;
    const int w = tid >> 6;
    const int h0 = lane * 8;
    const int e0 = ech * 16 + w * 4;

    int mk[4];
#pragma unroll
    for (int ei = 0; ei < 4; ++ei) mk[ei] = mask[(e0 + ei) * BATCH + b];

    float sv[8], sv2[4], spt[8][8];
    {
        float4 v0 = *(const float4*)(v + h0);
        float4 v1 = *(const float4*)(v + h0 + 4);
        sv[0] = -2.f * v0.x; sv[1] = -2.f * v0.y; sv[2] = -2.f * v0.z; sv[3] = -2.f * v0.w;
        sv[4] = -2.f * v1.x; sv[5] = -2.f * v1.y; sv[6] = -2.f * v1.z; sv[7] = -2.f * v1.w;
        sv2[0] = sv[0] + sv[1]; sv2[1] = sv[2] + sv[3];
        sv2[2] = sv[4] + sv[5]; sv2[3] = sv[6] + sv[7];
#pragma unroll
        for (int i = 0; i < 8; ++i) {
            const float* p = EPT + ((size_t)((tg * 8 + i) * BATCH + b)) * HID + h0;
            float4 p0 = *(const float4*)(p);
            float4 p1 = *(const float4*)(p + 4);
            spt[i][0] = p0.x; spt[i][1] = p0.y; spt[i][2] = p0.z; spt[i][3] = p0.w;
            spt[i][4] = p1.x; spt[i][5] = p1.y; spt[i][6] = p1.z; spt[i][7] = p1.w;
        }
    }
#pragma unroll
    for (int ei = 0; ei < 4; ++ei) {
        const int e = e0 + ei;
        if (mk[ei] != 0) {  // wave-uniform skip
            if (lane < 8)
                P[((size_t)b * T_LEN + tg * 8 + lane) * E_LEN + e] = 1e-30f;
            continue;
        }
        union { bf16x8 v8; __hip_bfloat16 h[8]; } pv;
        pv.v8 = *(const bf16x8*)(EPE + ((size_t)(e * BATCH + b)) * HID + h0);
        float pr[8];
#pragma unroll
        for (int j = 0; j < 8; ++j) pr[j] = __bfloat162float(pv.h[j]);
        float a[8] = {0.f, 0.f, 0.f, 0.f, 0.f, 0.f, 0.f, 0.f};
#pragma unroll
        for (int i = 0; i < 8; ++i) {
#pragma unroll
            for (int jq = 0; jq < 2; ++jq) {
                const int j0 = jq * 4;
                float a0 = spt[i][j0 + 0] * pr[j0 + 0];
                float a1 = spt[i][j0 + 1] * pr[j0 + 1];
                float a2 = spt[i][j0 + 2] * pr[j0 + 2];
                float a3 = spt[i][j0 + 3] * pr[j0 + 3];
                float u0 = a0 + 1.0f;
                float u2 = a2 + 1.0f;
                float d01 = fmaf(a1, u0, u0);           // (1+a0)(1+a1)
                float d23 = fmaf(a3, u2, u2);           // (1+a2)(1+a3)
                float n01 = fmaf(sv[j0 + 0], a1, fmaf(sv[j0 + 1], a0, sv2[jq * 2 + 0]));
                float n23 = fmaf(sv[j0 + 2], a3, fmaf(sv[j0 + 3], a2, sv2[jq * 2 + 1]));
                float nn = fmaf(n01, d23, n23 * d01);
                float dd = d01 * d23;
                a[i] = fmaf(nn, __builtin_amdgcn_rcpf(dd), a[i]);
            }
        }
#pragma unroll
        for (int i = 0; i < 8; ++i) {
            a[i] += __shfl_xor(a[i], 1);
            a[i] += __shfl_xor(a[i], 2);
            a[i] += __shfl_xor(a[i], 4);
            a[i] += __shfl_xor(a[i], 8);
        }
        const int sel = lane & 3;
        float uA = sel == 0 ? a[0] : sel == 1 ? a[1] : sel == 2 ? a[2] : a[3];
        float uB = sel == 0 ? a[4] : sel == 1 ? a[5] : sel == 2 ? a[6] : a[7];
        uA += __shfl_xor(uA, 16); uA += __shfl_xor(uA, 32);
        uB += __shfl_xor(uB, 16); uB += __shfl_xor(uB, 32);
        float uu = (lane & 4) ? uB : uA;
        if (lane < 8)
            P[((size_t)b * T_LEN + tg * 8 + lane) * E_LEN + e] =
                __builtin_amdgcn_exp2f(uu * LOG2E);
    }
}

// ---------------------------------------------------------------------------
// Phase C: fused epilogue on P, 768 units.
// units [0,512): new_exp, (b, e-chunk of 16, d-half). Wave: 4 e's.
// units [512,768): new_topic, (b, t-quad, d-half): weights for 4 t's
//   (one per wave) in LDS; e-loop sliced across waves (64 e each) with 4-t
//   register accumulators; LDS partial reduction.
// ---------------------------------------------------------------------------
__device__ __forceinline__ void epilogue_body(
    int u, int tid, float* smem,
    const float* __restrict__ P, const float* __restrict__ topic,
    const float* __restrict__ expo, float* __restrict__ out) {
    const int lane = tid & 63;
    const int w = tid >> 6;
    if (u < 512) {
        // ---- new_exp ----
        const int b = u >> 5;
        const int ech = (u >> 1) & 15;
        const int hf = u & 1;
        const int e0 = ech * 16 + w * 4;
        float wv[4];
#pragma unroll
        for (int ei = 0; ei < 4; ++ei) {
            const int e = e0 + ei;
            float x = (lane < T_LEN) ? P[((size_t)b * T_LEN + lane) * E_LEN + e] : 0.f;
            float s = x;
#pragma unroll
            for (int off = 32; off; off >>= 1) s += __shfl_xor(s, off);
            wv[ei] = x * __builtin_amdgcn_rcpf(s);
        }
        const int d0 = hf * 256 + lane * 4;
        float4 acc[4];
#pragma unroll
        for (int ei = 0; ei < 4; ++ei) acc[ei] = {0.f, 0.f, 0.f, 0.f};
        for (int t = 0; t < T_LEN; ++t) {
            float4 r = *(const float4*)(topic + ((size_t)t * BATCH + b) * DIM + d0);
            float wt[4];
#pragma unroll
            for (int ei = 0; ei < 4; ++ei) wt[ei] = __shfl(wv[ei], t);
#pragma unroll
            for (int ei = 0; ei < 4; ++ei) {
                acc[ei].x = fmaf(wt[ei], r.x, acc[ei].x);
                acc[ei].y = fmaf(wt[ei], r.y, acc[ei].y);
                acc[ei].z = fmaf(wt[ei], r.z, acc[ei].z);
                acc[ei].w = fmaf(wt[ei], r.w, acc[ei].w);
            }
        }
#pragma unroll
        for (int ei = 0; ei < 4; ++ei) {
            float* o = out + (size_t)BATCH * T_LEN * DIM +
                       ((size_t)b * E_LEN + e0 + ei) * DIM + d0;
            *(float4*)o = acc[ei];
        }
    } else {
        // ---- new_topic (t-quad) ----
        const int q = u - 512;            // [0,256)
        const int b = q >> 4;             // 16 b
        const int tq = (q >> 1) & 7;      // t-quad: t = tq*4 + {0..3}
        const int hf = q & 1;             // d-half
        // Phase 1: wave w computes softmax weights for t = tq*4 + w
        {
            const int bt = b * T_LEN + tq * 4 + w;
            float4 xv = *(const float4*)&P[(size_t)bt * E_LEN + lane * 4];
            float s = xv.x + xv.y + xv.z + xv.w;
#pragma unroll
            for (int off = 32; off; off >>= 1) s += __shfl_xor(s, off);
            float inv = __builtin_amdgcn_rcpf(s);
            float4 wvv = {xv.x * inv, xv.y * inv, xv.z * inv, xv.w * inv};
            *(float4*)&smem[w * 256 + lane * 4] = wvv;
        }
        __syncthreads();
        // Phase 2: wave w handles e in [w*64, w*64+64); lane owns 4 d's;
        // accumulates all 4 t's (each expo read reused 4x).
        const int dl = lane * 4;
        const int dglob = hf * 256 + dl;
        float4 a0 = {0.f, 0.f, 0.f, 0.f};
        float4 a1 = {0.f, 0.f, 0.f, 0.f};
        float4 a2 = {0.f, 0.f, 0.f, 0.f};
        float4 a3 = {0.f, 0.f, 0.f, 0.f};
        const float* base = expo + (size_t)b * DIM + dglob;
        for (int ee = 0; ee < 64; ++ee) {
            const int e = w * 64 + ee;
            float4 rv = *(const float4*)(base + (size_t)e * BATCH * DIM);
            float w0 = smem[e];
            float w1 = smem[256 + e];
            float w2 = smem[512 + e];
            float w3 = smem[768 + e];
            a0.x = fmaf(w0, rv.x, a0.x); a0.y = fmaf(w0, rv.y, a0.y);
            a0.z = fmaf(w0, rv.z, a0.z); a0.w = fmaf(w0, rv.w, a0.w);
            a1.x = fmaf(w1, rv.x, a1.x); a1.y = fmaf(w1, rv.y, a1.y);
            a1.z = fmaf(w1, rv.z, a1.z); a1.w = fmaf(w1, rv.w, a1.w);
            a2.x = fmaf(w2, rv.x, a2.x); a2.y = fmaf(w2, rv.y, a2.y);
            a2.z = fmaf(w2, rv.z, a2.z); a2.w = fmaf(w2, rv.w, a2.w);
            a3.x = fmaf(w3, rv.x, a3.x); a3.y = fmaf(w3, rv.y, a3.y);
            a3.z = fmaf(w3, rv.z, a3.z); a3.w = fmaf(w3, rv.w, a3.w);
        }
        // partials: [wave][t][256 d]
        *(float4*)&smem[1024 + (w * 4 + 0) * 256 + dl] = a0;
        *(float4*)&smem[1024 + (w * 4 + 1) * 256 + dl] = a1;
        *(float4*)&smem[1024 + (w * 4 + 2) * 256 + dl] = a2;
        *(float4*)&smem[1024 + (w * 4 + 3) * 256 + dl] = a3;
        __syncthreads();
        // Phase 3: 256 threads x 4 outputs: (tt, d=tid)
#pragma unroll
        for (int tt = 0; tt < 4; ++tt) {
            float sum = smem[1024 + (0 * 4 + tt) * 256 + tid] +
                        smem[1024 + (1 * 4 + tt) * 256 + tid] +
                        smem[1024 + (2 * 4 + tt) * 256 + tid] +
                        smem[1024 + (3 * 4 + tt) * 256 + tid];
            out[((size_t)b * T_LEN + tq * 4 + tt) * DIM + hf * 256 + tid] = sum;
        }
        __syncthreads();  // protect smem for any later grid-stride unit
    }
}

// ---------------------------------------------------------------------------
// Fused cooperative kernel: 512 blocks x 256 thr, 2 blocks/CU guaranteed
// (__launch_bounds__(256,2): VGPR<=256; LDS 20480B*2 = 40KB/CU).
// Grid-stride over 576 / 1024 / 768 virtual blocks with grid.sync() between.
// ---------------------------------------------------------------------------
__global__ __launch_bounds__(256, 2) void fused_k(
    const float* __restrict__ topic, const float* __restrict__ expo,
    const float* __restrict__ W, const float* __restrict__ battn,
    const float* __restrict__ vsc, const int* __restrict__ mask,
    float* __restrict__ EPT, __hip_bfloat16* __restrict__ EPE,
    float* __restrict__ P, float* __restrict__ out) {
    __shared__ __align__(16) float smem[5120];  // 20480 B: max(GEMM 18432, epi 20480)
    const int tid = threadIdx.x;
    const int bid = blockIdx.x;
    cg::grid_group grid = cg::this_grid();
    {
        __hip_bfloat16* As = (__hip_bfloat16*)smem;
        __hip_bfloat16* Bs = As + 64 * GLDR;
        for (int u = bid; u < 576; u += 512)
            gemm_body(u, tid, As, Bs, topic, expo, W, battn, EPT, EPE);
    }
    grid.sync();
    for (int u = bid; u < 1024; u += 512)
        energies_body(u, tid, EPT, EPE, vsc, mask, P);
    grid.sync();
    for (int u = bid; u < 768; u += 512)
        epilogue_body(u, tid, smem, P, topic, expo, out);
}

// ---------------------------------------------------------------------------
// Fallback path: original 3-kernel pipeline (same bodies), used only if the
// cooperative launch is rejected.
// ---------------------------------------------------------------------------
__global__ __launch_bounds__(256) void gemm_fused_k(
    const float* __restrict__ topic, const float* __restrict__ expo,
    const float* __restrict__ W, const float* __restrict__ battn,
    float* __restrict__ EPT, __hip_bfloat16* __restrict__ EPE) {
    __shared__ __align__(16) __hip_bfloat16 As[64 * GLDR];
    __shared__ __align__(16) __hip_bfloat16 Bs[64 * GLDR];
    gemm_body(blockIdx.x, threadIdx.x, As, Bs, topic, expo, W, battn, EPT, EPE);
}

__global__ __launch_bounds__(256) void energies_k(
    const float* __restrict__ EPT, const __hip_bfloat16* __restrict__ EPE,
    const float* __restrict__ v, const int* __restrict__ mask,
    float* __restrict__ P) {
    energies_body(blockIdx.x, threadIdx.x, EPT, EPE, v, mask, P);
}

__global__ __launch_bounds__(256) void epilogue_k(
    const float* __restrict__ P, const float* __restrict__ topic,
    const float* __restrict__ expo, float* __restrict__ out) {
    __shared__ __align__(16) float smem[5120];
    epilogue_body(blockIdx.x, threadIdx.x, smem, P, topic, expo, out);
}

extern "C" void kernel_launch(void* const* d_in, const int* in_sizes, int n_in,
                              void* d_out, int out_size, void* d_ws, size_t ws_size,
                              hipStream_t stream) {
    const float* topic = (const float*)d_in[0];   // [T,B,D]
    const float* expo  = (const float*)d_in[1];   // [E,B,D]
    const int*   mask  = (const int*)d_in[2];     // [E,B]
    const float* W     = (const float*)d_in[3];   // [H, H+D]
    const float* battn = (const float*)d_in[4];   // [H]
    const float* vsc   = (const float*)d_in[5];   // [1,H]
    float* out = (float*)d_out;                   // new_topic [B,T,D] ++ new_exp [B,E,D]

    float* EPT = (float*)d_ws;                                // [512,512] f32, 1 MB
    __hip_bfloat16* EPE = (__hip_bfloat16*)(EPT + 512 * 512); // [4096,512] bf16, 4 MB
    float* P = (float*)(EPE + (size_t)4096 * 512);            // [B,T,E] f32, 0.5 MB

    void* args[10] = {(void*)&topic, (void*)&expo, (void*)&W, (void*)&battn,
                      (void*)&vsc, (void*)&mask, (void*)&EPT, (void*)&EPE,
                      (void*)&P, (void*)&out};
    hipError_t err = hipLaunchCooperativeKernel((const void*)fused_k,
                                                dim3(512), dim3(256),
                                                args, 0, stream);
    if (err != hipSuccess) {
        gemm_fused_k<<<576, 256, 0, stream>>>(topic, expo, W, battn, EPT, EPE);
        energies_k<<<1024, 256, 0, stream>>>(EPT, EPE, vsc, mask, P);
        epilogue_k<<<768, 256, 0, stream>>>(P, topic, expo, out);
    }
}

// Round 2
// 120.282 us; speedup vs baseline: 2.0904x; 2.0904x over previous
//
#include <hip/hip_runtime.h>
#include <hip/hip_bf16.h>
#include <cstddef>
#include <cstdint>

#define T_LEN 32
#define E_LEN 256
#define BATCH 16
#define DIM 512
#define HID 512
#define WROW 1024  // HID + DIM

#define TWO_LOG2E 2.8853900817779268f  // 2*log2(e)
#define LOG2E 1.4426950408889634f

typedef __attribute__((ext_vector_type(8))) short bf16x8;
typedef __attribute__((ext_vector_type(4))) float f32x4;

__device__ inline bf16x8 cvt8(float4 a, float4 b) {
    union { bf16x8 v; __hip_bfloat16 h[8]; } u;
    u.h[0] = __float2bfloat16(a.x); u.h[1] = __float2bfloat16(a.y);
    u.h[2] = __float2bfloat16(a.z); u.h[3] = __float2bfloat16(a.w);
    u.h[4] = __float2bfloat16(b.x); u.h[5] = __float2bfloat16(b.y);
    u.h[6] = __float2bfloat16(b.z); u.h[7] = __float2bfloat16(b.w);
    return u.v;
}

#define GPAD 8
#define GLDR (64 + GPAD)   // 72 halfwords per LDS row

// ---------------------------------------------------------------------------
// Fused projection GEMM (NT), f32 in -> bf16 MFMA -> exp2 -> out.
// blk < 64:  EPT(f32)  = 2^(TWO_LOG2E*(topic @ W[:,:D]^T + b_attn))  (M=512)
// blk >= 64: EPE(bf16) = 2^(TWO_LOG2E*(expo @ W[:,D:]^T))            (M=4096)
// Tile 64x64, BK=64, 256 threads, register-double-buffered global loads.
// ---------------------------------------------------------------------------
__global__ __launch_bounds__(256) void gemm_fused_k(
    const float* __restrict__ topic, const float* __restrict__ expo,
    const float* __restrict__ W, const float* __restrict__ battn,
    float* __restrict__ EPT, __hip_bfloat16* __restrict__ EPE) {
    __shared__ __align__(16) __hip_bfloat16 As[64 * GLDR];
    __shared__ __align__(16) __hip_bfloat16 Bs[64 * GLDR];
    const int tid = threadIdx.x;
    const int by = blockIdx.x >> 3;       // 0..71
    const int n0 = (blockIdx.x & 7) * 64;
    const float* A; const float* Wp; int m0;
    const bool isT = (by < 8);
    if (isT) { A = topic; Wp = W;       m0 = by * 64; }
    else     { A = expo;  Wp = W + DIM; m0 = (by - 8) * 64; }
    const int w = tid >> 6;
    const int lane = tid & 63;
    const int l15 = lane & 15;
    const int g = lane >> 4;
    const int srow = tid >> 2;   // 0..63
    const int sc = tid & 3;      // halfword chunks at sc*8 and sc*8+32

    f32x4 acc[4];
    const f32x4 z = {0.f, 0.f, 0.f, 0.f};
#pragma unroll
    for (int nt = 0; nt < 4; ++nt) acc[nt] = z;

    const float* ga = A + (size_t)(m0 + srow) * 512 + sc * 8;
    const float* gb = Wp + (size_t)(n0 + srow) * WROW + sc * 8;

    float4 a0 = *(const float4*)(ga);
    float4 a1 = *(const float4*)(ga + 4);
    float4 a2 = *(const float4*)(ga + 32);
    float4 a3 = *(const float4*)(ga + 36);
    float4 b0 = *(const float4*)(gb);
    float4 b1 = *(const float4*)(gb + 4);
    float4 b2 = *(const float4*)(gb + 32);
    float4 b3 = *(const float4*)(gb + 36);

    for (int kk = 0; kk < 8; ++kk) {
        bf16x8 av0 = cvt8(a0, a1), av1 = cvt8(a2, a3);
        bf16x8 bv0 = cvt8(b0, b1), bv1 = cvt8(b2, b3);
        if (kk < 7) {  // prefetch next K-chunk while this one computes
            ga += 64; gb += 64;
            a0 = *(const float4*)(ga);
            a1 = *(const float4*)(ga + 4);
            a2 = *(const float4*)(ga + 32);
            a3 = *(const float4*)(ga + 36);
            b0 = *(const float4*)(gb);
            b1 = *(const float4*)(gb + 4);
            b2 = *(const float4*)(gb + 32);
            b3 = *(const float4*)(gb + 36);
        }
        __syncthreads();
        *(bf16x8*)&As[srow * GLDR + sc * 8] = av0;
        *(bf16x8*)&As[srow * GLDR + sc * 8 + 32] = av1;
        *(bf16x8*)&Bs[srow * GLDR + sc * 8] = bv0;
        *(bf16x8*)&Bs[srow * GLDR + sc * 8 + 32] = bv1;
        __syncthreads();
#pragma unroll
        for (int s = 0; s < 2; ++s) {
            bf16x8 af = *(const bf16x8*)&As[(w * 16 + l15) * GLDR + (s * 4 + g) * 8];
#pragma unroll
            for (int nt = 0; nt < 4; ++nt) {
                bf16x8 bf = *(const bf16x8*)&Bs[(nt * 16 + l15) * GLDR + (s * 4 + g) * 8];
                acc[nt] = __builtin_amdgcn_mfma_f32_16x16x32_bf16(af, bf, acc[nt], 0, 0, 0);
            }
        }
    }
    if (isT) {
#pragma unroll
        for (int nt = 0; nt < 4; ++nt) {
            int n = n0 + nt * 16 + l15;
            float bv = battn[n];
#pragma unroll
            for (int r = 0; r < 4; ++r) {
                int m = m0 + w * 16 + g * 4 + r;
                EPT[(size_t)m * 512 + n] =
                    __builtin_amdgcn_exp2f((acc[nt][r] + bv) * TWO_LOG2E);
            }
        }
    } else {
#pragma unroll
        for (int nt = 0; nt < 4; ++nt) {
            int n = n0 + nt * 16 + l15;
#pragma unroll
            for (int r = 0; r < 4; ++r) {
                int m = m0 + w * 16 + g * 4 + r;
                EPE[(size_t)m * 512 + n] = __float2bfloat16(
                    __builtin_amdgcn_exp2f(acc[nt][r] * TWO_LOG2E));
            }
        }
    }
}

// ---------------------------------------------------------------------------
// Energies -> P = exp(energy - const(sum v + b_score)); masked -> 1e-30.
// 4-way reciprocal combining (validated in round 1, absmax unchanged):
//   sum_{j quad} sv_j/(1+a_j) = N/D, 15 full-rate VALU + 1 rcp per quad
//   (was 8 fma + 4 rcp). a_j >= 0 (product of exps): no cancellation;
//   D <= e^80 < f32 max in practice; saturated tails round to 0 correctly.
// Wave: 4 e's x 8 t's; block = (b, 8 t's, 16 e's); grid 1024.
// ---------------------------------------------------------------------------
__global__ __launch_bounds__(256) void energies_k(
    const float* __restrict__ EPT, const __hip_bfloat16* __restrict__ EPE,
    const float* __restrict__ v, const int* __restrict__ mask,
    float* __restrict__ P) {
    const int u = blockIdx.x;
    const int b = u & 15;
    const int tg = (u >> 4) & 3;   // t = tg*8 + i
    const int ech = u >> 6;        // e base = ech*16
    const int tid = threadIdx.x;
    const int lane = tid & 63;
    const int w = tid >> 6;
    const int h0 = lane * 8;
    const int e0 = ech * 16 + w * 4;

    int mk[4];
#pragma unroll
    for (int ei = 0; ei < 4; ++ei) mk[ei] = mask[(e0 + ei) * BATCH + b];

    float sv[8], sv2[4], spt[8][8];
    {
        float4 v0 = *(const float4*)(v + h0);
        float4 v1 = *(const float4*)(v + h0 + 4);
        sv[0] = -2.f * v0.x; sv[1] = -2.f * v0.y; sv[2] = -2.f * v0.z; sv[3] = -2.f * v0.w;
        sv[4] = -2.f * v1.x; sv[5] = -2.f * v1.y; sv[6] = -2.f * v1.z; sv[7] = -2.f * v1.w;
        sv2[0] = sv[0] + sv[1]; sv2[1] = sv[2] + sv[3];
        sv2[2] = sv[4] + sv[5]; sv2[3] = sv[6] + sv[7];
#pragma unroll
        for (int i = 0; i < 8; ++i) {
            const float* p = EPT + ((size_t)((tg * 8 + i) * BATCH + b)) * HID + h0;
            float4 p0 = *(const float4*)(p);
            float4 p1 = *(const float4*)(p + 4);
            spt[i][0] = p0.x; spt[i][1] = p0.y; spt[i][2] = p0.z; spt[i][3] = p0.w;
            spt[i][4] = p1.x; spt[i][5] = p1.y; spt[i][6] = p1.z; spt[i][7] = p1.w;
        }
    }
#pragma unroll
    for (int ei = 0; ei < 4; ++ei) {
        const int e = e0 + ei;
        if (mk[ei] != 0) {  // wave-uniform skip
            if (lane < 8)
                P[((size_t)b * T_LEN + tg * 8 + lane) * E_LEN + e] = 1e-30f;
            continue;
        }
        union { bf16x8 v8; __hip_bfloat16 h[8]; } pv;
        pv.v8 = *(const bf16x8*)(EPE + ((size_t)(e * BATCH + b)) * HID + h0);
        float pr[8];
#pragma unroll
        for (int j = 0; j < 8; ++j) pr[j] = __bfloat162float(pv.h[j]);
        float a[8] = {0.f, 0.f, 0.f, 0.f, 0.f, 0.f, 0.f, 0.f};
#pragma unroll
        for (int i = 0; i < 8; ++i) {
#pragma unroll
            for (int jq = 0; jq < 2; ++jq) {
                const int j0 = jq * 4;
                float a0 = spt[i][j0 + 0] * pr[j0 + 0];
                float a1 = spt[i][j0 + 1] * pr[j0 + 1];
                float a2 = spt[i][j0 + 2] * pr[j0 + 2];
                float a3 = spt[i][j0 + 3] * pr[j0 + 3];
                float u0 = a0 + 1.0f;
                float u2 = a2 + 1.0f;
                float d01 = fmaf(a1, u0, u0);           // (1+a0)(1+a1)
                float d23 = fmaf(a3, u2, u2);           // (1+a2)(1+a3)
                float n01 = fmaf(sv[j0 + 0], a1, fmaf(sv[j0 + 1], a0, sv2[jq * 2 + 0]));
                float n23 = fmaf(sv[j0 + 2], a3, fmaf(sv[j0 + 3], a2, sv2[jq * 2 + 1]));
                float nn = fmaf(n01, d23, n23 * d01);
                float dd = d01 * d23;
                a[i] = fmaf(nn, __builtin_amdgcn_rcpf(dd), a[i]);
            }
        }
#pragma unroll
        for (int i = 0; i < 8; ++i) {
            a[i] += __shfl_xor(a[i], 1);
            a[i] += __shfl_xor(a[i], 2);
            a[i] += __shfl_xor(a[i], 4);
            a[i] += __shfl_xor(a[i], 8);
        }
        const int sel = lane & 3;
        float uA = sel == 0 ? a[0] : sel == 1 ? a[1] : sel == 2 ? a[2] : a[3];
        float uB = sel == 0 ? a[4] : sel == 1 ? a[5] : sel == 2 ? a[6] : a[7];
        uA += __shfl_xor(uA, 16); uA += __shfl_xor(uA, 32);
        uB += __shfl_xor(uB, 16); uB += __shfl_xor(uB, 32);
        float uu = (lane & 4) ? uB : uA;
        if (lane < 8)
            P[((size_t)b * T_LEN + tg * 8 + lane) * E_LEN + e] =
                __builtin_amdgcn_exp2f(uu * LOG2E);
    }
}

// ---------------------------------------------------------------------------
// Fused epilogue on P, 640 blocks.
// blocks [0,512): new_exp, block=(b, e-chunk of 16, d-half). Wave: 4 e's.
// blocks [512,640): new_topic, block=(b, t-OCT, d-half): weights for 8 t's
//   in LDS transposed [e][8] (2x ds_read_b128 broadcast per e); e-loop sliced
//   across waves (64 e each) with 8-t register accumulators; LDS partial
//   reduction. Expo traffic 32 MB total (was 64 MB with t-quads).
// ---------------------------------------------------------------------------
__global__ __launch_bounds__(256) void epilogue_k(
    const float* __restrict__ P, const float* __restrict__ topic,
    const float* __restrict__ expo, float* __restrict__ out) {
    __shared__ __align__(16) float smem[10240];  // [0,2048): weights[e][8]; [2048,10240): partials
    const int tid = threadIdx.x;
    const int lane = tid & 63;
    const int w = tid >> 6;
    if (blockIdx.x < 512) {
        // ---- new_exp ----
        const int b = blockIdx.x >> 5;
        const int ech = (blockIdx.x >> 1) & 15;
        const int hf = blockIdx.x & 1;
        const int e0 = ech * 16 + w * 4;
        float wv[4];
#pragma unroll
        for (int ei = 0; ei < 4; ++ei) {
            const int e = e0 + ei;
            float x = (lane < T_LEN) ? P[((size_t)b * T_LEN + lane) * E_LEN + e] : 0.f;
            float s = x;
#pragma unroll
            for (int off = 32; off; off >>= 1) s += __shfl_xor(s, off);
            wv[ei] = x * __builtin_amdgcn_rcpf(s);
        }
        const int d0 = hf * 256 + lane * 4;
        float4 acc[4];
#pragma unroll
        for (int ei = 0; ei < 4; ++ei) acc[ei] = {0.f, 0.f, 0.f, 0.f};
        for (int t = 0; t < T_LEN; ++t) {
            float4 r = *(const float4*)(topic + ((size_t)t * BATCH + b) * DIM + d0);
            float wt[4];
#pragma unroll
            for (int ei = 0; ei < 4; ++ei) wt[ei] = __shfl(wv[ei], t);
#pragma unroll
            for (int ei = 0; ei < 4; ++ei) {
                acc[ei].x = fmaf(wt[ei], r.x, acc[ei].x);
                acc[ei].y = fmaf(wt[ei], r.y, acc[ei].y);
                acc[ei].z = fmaf(wt[ei], r.z, acc[ei].z);
                acc[ei].w = fmaf(wt[ei], r.w, acc[ei].w);
            }
        }
#pragma unroll
        for (int ei = 0; ei < 4; ++ei) {
            float* o = out + (size_t)BATCH * T_LEN * DIM +
                       ((size_t)b * E_LEN + e0 + ei) * DIM + d0;
            *(float4*)o = acc[ei];
        }
    } else {
        // ---- new_topic (t-oct) ----
        const int q = blockIdx.x - 512;   // [0,128)
        const int b = q >> 3;             // 16 b
        const int to = (q >> 1) & 3;      // t-oct: t = to*8 + {0..7}
        const int hf = q & 1;             // d-half
        // Phase 1: wave w computes softmax weights for tt = w and w+4;
        // store transposed: smem[e*8 + tt].
#pragma unroll
        for (int ti = 0; ti < 2; ++ti) {
            const int tt = w + ti * 4;    // 0..7
            const int bt = b * T_LEN + to * 8 + tt;
            float4 xv = *(const float4*)&P[(size_t)bt * E_LEN + lane * 4];
            float s = xv.x + xv.y + xv.z + xv.w;
#pragma unroll
            for (int off = 32; off; off >>= 1) s += __shfl_xor(s, off);
            float inv = __builtin_amdgcn_rcpf(s);
            smem[(lane * 4 + 0) * 8 + tt] = xv.x * inv;
            smem[(lane * 4 + 1) * 8 + tt] = xv.y * inv;
            smem[(lane * 4 + 2) * 8 + tt] = xv.z * inv;
            smem[(lane * 4 + 3) * 8 + tt] = xv.w * inv;
        }
        __syncthreads();
        // Phase 2: wave w handles e in [w*64, w*64+64); lane owns 4 d's;
        // accumulates all 8 t's (each expo read reused 8x).
        const int dl = lane * 4;
        const int dglob = hf * 256 + dl;
        float4 acc[8];
#pragma unroll
        for (int tt = 0; tt < 8; ++tt) acc[tt] = {0.f, 0.f, 0.f, 0.f};
        const float* base = expo + (size_t)b * DIM + dglob;
#pragma unroll 2
        for (int ee = 0; ee < 64; ++ee) {
            const int e = w * 64 + ee;
            float4 rv = *(const float4*)(base + (size_t)e * BATCH * DIM);
            float4 w0 = *(const float4*)&smem[e * 8];      // broadcast
            float4 w1 = *(const float4*)&smem[e * 8 + 4];  // broadcast
            acc[0].x = fmaf(w0.x, rv.x, acc[0].x); acc[0].y = fmaf(w0.x, rv.y, acc[0].y);
            acc[0].z = fmaf(w0.x, rv.z, acc[0].z); acc[0].w = fmaf(w0.x, rv.w, acc[0].w);
            acc[1].x = fmaf(w0.y, rv.x, acc[1].x); acc[1].y = fmaf(w0.y, rv.y, acc[1].y);
            acc[1].z = fmaf(w0.y, rv.z, acc[1].z); acc[1].w = fmaf(w0.y, rv.w, acc[1].w);
            acc[2].x = fmaf(w0.z, rv.x, acc[2].x); acc[2].y = fmaf(w0.z, rv.y, acc[2].y);
            acc[2].z = fmaf(w0.z, rv.z, acc[2].z); acc[2].w = fmaf(w0.z, rv.w, acc[2].w);
            acc[3].x = fmaf(w0.w, rv.x, acc[3].x); acc[3].y = fmaf(w0.w, rv.y, acc[3].y);
            acc[3].z = fmaf(w0.w, rv.z, acc[3].z); acc[3].w = fmaf(w0.w, rv.w, acc[3].w);
            acc[4].x = fmaf(w1.x, rv.x, acc[4].x); acc[4].y = fmaf(w1.x, rv.y, acc[4].y);
            acc[4].z = fmaf(w1.x, rv.z, acc[4].z); acc[4].w = fmaf(w1.x, rv.w, acc[4].w);
            acc[5].x = fmaf(w1.y, rv.x, acc[5].x); acc[5].y = fmaf(w1.y, rv.y, acc[5].y);
            acc[5].z = fmaf(w1.y, rv.z, acc[5].z); acc[5].w = fmaf(w1.y, rv.w, acc[5].w);
            acc[6].x = fmaf(w1.z, rv.x, acc[6].x); acc[6].y = fmaf(w1.z, rv.y, acc[6].y);
            acc[6].z = fmaf(w1.z, rv.z, acc[6].z); acc[6].w = fmaf(w1.z, rv.w, acc[6].w);
            acc[7].x = fmaf(w1.w, rv.x, acc[7].x); acc[7].y = fmaf(w1.w, rv.y, acc[7].y);
            acc[7].z = fmaf(w1.w, rv.z, acc[7].z); acc[7].w = fmaf(w1.w, rv.w, acc[7].w);
        }
        // partials: [wave][8 t][256 d] at float offset 2048
#pragma unroll
        for (int tt = 0; tt < 8; ++tt)
            *(float4*)&smem[2048 + (w * 8 + tt) * 256 + dl] = acc[tt];
        __syncthreads();
        // Phase 3: 256 threads x 8 outputs: (tt, d=tid)
#pragma unroll
        for (int tt = 0; tt < 8; ++tt) {
            float sum = smem[2048 + (0 * 8 + tt) * 256 + tid] +
                        smem[2048 + (1 * 8 + tt) * 256 + tid] +
                        smem[2048 + (2 * 8 + tt) * 256 + tid] +
                        smem[2048 + (3 * 8 + tt) * 256 + tid];
            out[((size_t)b * T_LEN + to * 8 + tt) * DIM + hf * 256 + tid] = sum;
        }
    }
}

extern "C" void kernel_launch(void* const* d_in, const int* in_sizes, int n_in,
                              void* d_out, int out_size, void* d_ws, size_t ws_size,
                              hipStream_t stream) {
    const float* topic = (const float*)d_in[0];   // [T,B,D]
    const float* expo  = (const float*)d_in[1];   // [E,B,D]
    const int*   mask  = (const int*)d_in[2];     // [E,B]
    const float* W     = (const float*)d_in[3];   // [H, H+D]
    const float* battn = (const float*)d_in[4];   // [H]
    const float* vsc   = (const float*)d_in[5];   // [1,H]
    float* out = (float*)d_out;                   // new_topic [B,T,D] ++ new_exp [B,E,D]

    float* EPT = (float*)d_ws;                                // [512,512] f32, 1 MB
    __hip_bfloat16* EPE = (__hip_bfloat16*)(EPT + 512 * 512); // [4096,512] bf16, 4 MB
    float* P = (float*)(EPE + (size_t)4096 * 512);            // [B,T,E] f32, 0.5 MB

    gemm_fused_k<<<576, 256, 0, stream>>>(topic, expo, W, battn, EPT, EPE);
    energies_k<<<1024, 256, 0, stream>>>(EPT, EPE, vsc, mask, P);
    epilogue_k<<<640, 256, 0, stream>>>(P, topic, expo, out);
}

// Round 3
// 113.645 us; speedup vs baseline: 2.2125x; 1.0584x over previous
//
#include <hip/hip_runtime.h>
#include <hip/hip_bf16.h>
#include <cstddef>
#include <cstdint>

#define T_LEN 32
#define E_LEN 256
#define BATCH 16
#define DIM 512
#define HID 512
#define WROW 1024  // HID + DIM

#define TWO_LOG2E 2.8853900817779268f  // 2*log2(e)
#define LOG2E 1.4426950408889634f

typedef __attribute__((ext_vector_type(8))) short bf16x8;
typedef __attribute__((ext_vector_type(4))) float f32x4;

__device__ inline bf16x8 cvt8(float4 a, float4 b) {
    union { bf16x8 v; __hip_bfloat16 h[8]; } u;
    u.h[0] = __float2bfloat16(a.x); u.h[1] = __float2bfloat16(a.y);
    u.h[2] = __float2bfloat16(a.z); u.h[3] = __float2bfloat16(a.w);
    u.h[4] = __float2bfloat16(b.x); u.h[5] = __float2bfloat16(b.y);
    u.h[6] = __float2bfloat16(b.z); u.h[7] = __float2bfloat16(b.w);
    return u.v;
}

#define GPAD 8
#define GLDR (64 + GPAD)   // 72 halfwords per LDS row

// ---------------------------------------------------------------------------
// Fused projection GEMM (NT), f32 in -> bf16 MFMA -> exp2 -> out.
// blk < 64:  EPT(f32)  = 2^(TWO_LOG2E*(topic @ W[:,:D]^T + b_attn))  (M=512)
// blk >= 64: EPE(bf16) = 2^(TWO_LOG2E*(expo @ W[:,D:]^T))            (M=4096)
// Tile 64x64, BK=64, 256 threads, register-prefetched global loads,
// LDS double-buffered: ONE __syncthreads per K-step (write(k+2) is
// separated from read(k) by bar(k+1); lgkmcnt before MFMA(k) completes
// the reads before the thread reaches bar(k+1)).
// ---------------------------------------------------------------------------
__global__ __launch_bounds__(256) void gemm_fused_k(
    const float* __restrict__ topic, const float* __restrict__ expo,
    const float* __restrict__ W, const float* __restrict__ battn,
    float* __restrict__ EPT, __hip_bfloat16* __restrict__ EPE) {
    __shared__ __align__(16) __hip_bfloat16 As[2][64 * GLDR];
    __shared__ __align__(16) __hip_bfloat16 Bs[2][64 * GLDR];
    const int tid = threadIdx.x;
    const int by = blockIdx.x >> 3;       // 0..71
    const int n0 = (blockIdx.x & 7) * 64;
    const float* A; const float* Wp; int m0;
    const bool isT = (by < 8);
    if (isT) { A = topic; Wp = W;       m0 = by * 64; }
    else     { A = expo;  Wp = W + DIM; m0 = (by - 8) * 64; }
    const int w = tid >> 6;
    const int lane = tid & 63;
    const int l15 = lane & 15;
    const int g = lane >> 4;
    const int srow = tid >> 2;   // 0..63
    const int sc = tid & 3;      // halfword chunks at sc*8 and sc*8+32

    f32x4 acc[4];
    const f32x4 z = {0.f, 0.f, 0.f, 0.f};
#pragma unroll
    for (int nt = 0; nt < 4; ++nt) acc[nt] = z;

    const float* ga = A + (size_t)(m0 + srow) * 512 + sc * 8;
    const float* gb = Wp + (size_t)(n0 + srow) * WROW + sc * 8;

    float4 a0 = *(const float4*)(ga);
    float4 a1 = *(const float4*)(ga + 4);
    float4 a2 = *(const float4*)(ga + 32);
    float4 a3 = *(const float4*)(ga + 36);
    float4 b0 = *(const float4*)(gb);
    float4 b1 = *(const float4*)(gb + 4);
    float4 b2 = *(const float4*)(gb + 32);
    float4 b3 = *(const float4*)(gb + 36);

    for (int kk = 0; kk < 8; ++kk) {
        const int cur = kk & 1;
        bf16x8 av0 = cvt8(a0, a1), av1 = cvt8(a2, a3);
        bf16x8 bv0 = cvt8(b0, b1), bv1 = cvt8(b2, b3);
        if (kk < 7) {  // prefetch next K-chunk while this one computes
            ga += 64; gb += 64;
            a0 = *(const float4*)(ga);
            a1 = *(const float4*)(ga + 4);
            a2 = *(const float4*)(ga + 32);
            a3 = *(const float4*)(ga + 36);
            b0 = *(const float4*)(gb);
            b1 = *(const float4*)(gb + 4);
            b2 = *(const float4*)(gb + 32);
            b3 = *(const float4*)(gb + 36);
        }
        *(bf16x8*)&As[cur][srow * GLDR + sc * 8] = av0;
        *(bf16x8*)&As[cur][srow * GLDR + sc * 8 + 32] = av1;
        *(bf16x8*)&Bs[cur][srow * GLDR + sc * 8] = bv0;
        *(bf16x8*)&Bs[cur][srow * GLDR + sc * 8 + 32] = bv1;
        __syncthreads();
#pragma unroll
        for (int s = 0; s < 2; ++s) {
            bf16x8 af = *(const bf16x8*)&As[cur][(w * 16 + l15) * GLDR + (s * 4 + g) * 8];
#pragma unroll
            for (int nt = 0; nt < 4; ++nt) {
                bf16x8 bf = *(const bf16x8*)&Bs[cur][(nt * 16 + l15) * GLDR + (s * 4 + g) * 8];
                acc[nt] = __builtin_amdgcn_mfma_f32_16x16x32_bf16(af, bf, acc[nt], 0, 0, 0);
            }
        }
    }
    if (isT) {
#pragma unroll
        for (int nt = 0; nt < 4; ++nt) {
            int n = n0 + nt * 16 + l15;
            float bv = battn[n];
#pragma unroll
            for (int r = 0; r < 4; ++r) {
                int m = m0 + w * 16 + g * 4 + r;
                EPT[(size_t)m * 512 + n] =
                    __builtin_amdgcn_exp2f((acc[nt][r] + bv) * TWO_LOG2E);
            }
        }
    } else {
#pragma unroll
        for (int nt = 0; nt < 4; ++nt) {
            int n = n0 + nt * 16 + l15;
#pragma unroll
            for (int r = 0; r < 4; ++r) {
                int m = m0 + w * 16 + g * 4 + r;
                EPE[(size_t)m * 512 + n] = __float2bfloat16(
                    __builtin_amdgcn_exp2f(acc[nt][r] * TWO_LOG2E));
            }
        }
    }
}

// ---------------------------------------------------------------------------
// Energies -> P = exp(energy - const(sum v + b_score)); masked -> 1e-30.
// 4-way reciprocal combining (validated R1/R2, absmax unchanged):
//   sum_{j quad} sv_j/(1+a_j) = N/D, 15 full-rate VALU + 1 rcp per quad
//   (was 8 fma + 4 rcp = 24 VALU-eq; now 19). a_j >= 0 (product of exps):
//   no cancellation; saturated tails round correctly.
// Wave: 4 e's x 8 t's; block = (b, 8 t's, 16 e's); grid 1024.
// ---------------------------------------------------------------------------
__global__ __launch_bounds__(256) void energies_k(
    const float* __restrict__ EPT, const __hip_bfloat16* __restrict__ EPE,
    const float* __restrict__ v, const int* __restrict__ mask,
    float* __restrict__ P) {
    const int u = blockIdx.x;
    const int b = u & 15;
    const int tg = (u >> 4) & 3;   // t = tg*8 + i
    const int ech = u >> 6;        // e base = ech*16
    const int tid = threadIdx.x;
    const int lane = tid & 63;
    const int w = tid >> 6;
    const int h0 = lane * 8;
    const int e0 = ech * 16 + w * 4;

    int mk[4];
#pragma unroll
    for (int ei = 0; ei < 4; ++ei) mk[ei] = mask[(e0 + ei) * BATCH + b];

    float sv[8], sv2[4], spt[8][8];
    {
        float4 v0 = *(const float4*)(v + h0);
        float4 v1 = *(const float4*)(v + h0 + 4);
        sv[0] = -2.f * v0.x; sv[1] = -2.f * v0.y; sv[2] = -2.f * v0.z; sv[3] = -2.f * v0.w;
        sv[4] = -2.f * v1.x; sv[5] = -2.f * v1.y; sv[6] = -2.f * v1.z; sv[7] = -2.f * v1.w;
        sv2[0] = sv[0] + sv[1]; sv2[1] = sv[2] + sv[3];
        sv2[2] = sv[4] + sv[5]; sv2[3] = sv[6] + sv[7];
#pragma unroll
        for (int i = 0; i < 8; ++i) {
            const float* p = EPT + ((size_t)((tg * 8 + i) * BATCH + b)) * HID + h0;
            float4 p0 = *(const float4*)(p);
            float4 p1 = *(const float4*)(p + 4);
            spt[i][0] = p0.x; spt[i][1] = p0.y; spt[i][2] = p0.z; spt[i][3] = p0.w;
            spt[i][4] = p1.x; spt[i][5] = p1.y; spt[i][6] = p1.z; spt[i][7] = p1.w;
        }
    }
#pragma unroll
    for (int ei = 0; ei < 4; ++ei) {
        const int e = e0 + ei;
        if (mk[ei] != 0) {  // wave-uniform skip
            if (lane < 8)
                P[((size_t)b * T_LEN + tg * 8 + lane) * E_LEN + e] = 1e-30f;
            continue;
        }
        union { bf16x8 v8; __hip_bfloat16 h[8]; } pv;
        pv.v8 = *(const bf16x8*)(EPE + ((size_t)(e * BATCH + b)) * HID + h0);
        float pr[8];
#pragma unroll
        for (int j = 0; j < 8; ++j) pr[j] = __bfloat162float(pv.h[j]);
        float a[8] = {0.f, 0.f, 0.f, 0.f, 0.f, 0.f, 0.f, 0.f};
#pragma unroll
        for (int i = 0; i < 8; ++i) {
#pragma unroll
            for (int jq = 0; jq < 2; ++jq) {
                const int j0 = jq * 4;
                float a0 = spt[i][j0 + 0] * pr[j0 + 0];
                float a1 = spt[i][j0 + 1] * pr[j0 + 1];
                float a2 = spt[i][j0 + 2] * pr[j0 + 2];
                float a3 = spt[i][j0 + 3] * pr[j0 + 3];
                float u0 = a0 + 1.0f;
                float u2 = a2 + 1.0f;
                float d01 = fmaf(a1, u0, u0);           // (1+a0)(1+a1)
                float d23 = fmaf(a3, u2, u2);           // (1+a2)(1+a3)
                float n01 = fmaf(sv[j0 + 0], a1, fmaf(sv[j0 + 1], a0, sv2[jq * 2 + 0]));
                float n23 = fmaf(sv[j0 + 2], a3, fmaf(sv[j0 + 3], a2, sv2[jq * 2 + 1]));
                float nn = fmaf(n01, d23, n23 * d01);
                float dd = d01 * d23;
                a[i] = fmaf(nn, __builtin_amdgcn_rcpf(dd), a[i]);
            }
        }
#pragma unroll
        for (int i = 0; i < 8; ++i) {
            a[i] += __shfl_xor(a[i], 1);
            a[i] += __shfl_xor(a[i], 2);
            a[i] += __shfl_xor(a[i], 4);
            a[i] += __shfl_xor(a[i], 8);
        }
        const int sel = lane & 3;
        float uA = sel == 0 ? a[0] : sel == 1 ? a[1] : sel == 2 ? a[2] : a[3];
        float uB = sel == 0 ? a[4] : sel == 1 ? a[5] : sel == 2 ? a[6] : a[7];
        uA += __shfl_xor(uA, 16); uA += __shfl_xor(uA, 32);
        uB += __shfl_xor(uB, 16); uB += __shfl_xor(uB, 32);
        float uu = (lane & 4) ? uB : uA;
        if (lane < 8)
            P[((size_t)b * T_LEN + tg * 8 + lane) * E_LEN + e] =
                __builtin_amdgcn_exp2f(uu * LOG2E);
    }
}

// ---------------------------------------------------------------------------
// Fused epilogue on P, 768 blocks (R0 t-quad version — t-oct regressed:
// 64-way bank-conflict phase-1 stores + latency-bound 128-block phase-2).
// blocks [0,512): new_exp, block=(b, e-chunk of 16, d-half). Wave: 4 e's.
// blocks [512,768): new_topic, block=(b, t-quad, d-half): weights for 4 t's
//   (one per wave) in LDS; e-loop sliced across waves (64 e each) with 4-t
//   register accumulators; LDS partial reduction.
// ---------------------------------------------------------------------------
__global__ __launch_bounds__(256) void epilogue_k(
    const float* __restrict__ P, const float* __restrict__ topic,
    const float* __restrict__ expo, float* __restrict__ out) {
    __shared__ __align__(16) float smem[5120];  // [0,1024): weights; [1024,5120): partials
    const int tid = threadIdx.x;
    const int lane = tid & 63;
    const int w = tid >> 6;
    if (blockIdx.x < 512) {
        // ---- new_exp ----
        const int b = blockIdx.x >> 5;
        const int ech = (blockIdx.x >> 1) & 15;
        const int hf = blockIdx.x & 1;
        const int e0 = ech * 16 + w * 4;
        float wv[4];
#pragma unroll
        for (int ei = 0; ei < 4; ++ei) {
            const int e = e0 + ei;
            float x = (lane < T_LEN) ? P[((size_t)b * T_LEN + lane) * E_LEN + e] : 0.f;
            float s = x;
#pragma unroll
            for (int off = 32; off; off >>= 1) s += __shfl_xor(s, off);
            wv[ei] = x * __builtin_amdgcn_rcpf(s);
        }
        const int d0 = hf * 256 + lane * 4;
        float4 acc[4];
#pragma unroll
        for (int ei = 0; ei < 4; ++ei) acc[ei] = {0.f, 0.f, 0.f, 0.f};
        for (int t = 0; t < T_LEN; ++t) {
            float4 r = *(const float4*)(topic + ((size_t)t * BATCH + b) * DIM + d0);
            float wt[4];
#pragma unroll
            for (int ei = 0; ei < 4; ++ei) wt[ei] = __shfl(wv[ei], t);
#pragma unroll
            for (int ei = 0; ei < 4; ++ei) {
                acc[ei].x = fmaf(wt[ei], r.x, acc[ei].x);
                acc[ei].y = fmaf(wt[ei], r.y, acc[ei].y);
                acc[ei].z = fmaf(wt[ei], r.z, acc[ei].z);
                acc[ei].w = fmaf(wt[ei], r.w, acc[ei].w);
            }
        }
#pragma unroll
        for (int ei = 0; ei < 4; ++ei) {
            float* o = out + (size_t)BATCH * T_LEN * DIM +
                       ((size_t)b * E_LEN + e0 + ei) * DIM + d0;
            *(float4*)o = acc[ei];
        }
    } else {
        // ---- new_topic (t-quad) ----
        const int q = blockIdx.x - 512;   // [0,256)
        const int b = q >> 4;             // 16 b
        const int tq = (q >> 1) & 7;      // t-quad: t = tq*4 + {0..3}
        const int hf = q & 1;             // d-half
        // Phase 1: wave w computes softmax weights for t = tq*4 + w
        {
            const int bt = b * T_LEN + tq * 4 + w;
            float4 xv = *(const float4*)&P[(size_t)bt * E_LEN + lane * 4];
            float s = xv.x + xv.y + xv.z + xv.w;
#pragma unroll
            for (int off = 32; off; off >>= 1) s += __shfl_xor(s, off);
            float inv = __builtin_amdgcn_rcpf(s);
            float4 wvv = {xv.x * inv, xv.y * inv, xv.z * inv, xv.w * inv};
            *(float4*)&smem[w * 256 + lane * 4] = wvv;
        }
        __syncthreads();
        // Phase 2: wave w handles e in [w*64, w*64+64); lane owns 4 d's;
        // accumulates all 4 t's (each expo read reused 4x).
        const int dl = lane * 4;
        const int dglob = hf * 256 + dl;
        float4 a0 = {0.f, 0.f, 0.f, 0.f};
        float4 a1 = {0.f, 0.f, 0.f, 0.f};
        float4 a2 = {0.f, 0.f, 0.f, 0.f};
        float4 a3 = {0.f, 0.f, 0.f, 0.f};
        const float* base = expo + (size_t)b * DIM + dglob;
        for (int ee = 0; ee < 64; ++ee) {
            const int e = w * 64 + ee;
            float4 rv = *(const float4*)(base + (size_t)e * BATCH * DIM);
            float w0 = smem[e];
            float w1 = smem[256 + e];
            float w2 = smem[512 + e];
            float w3 = smem[768 + e];
            a0.x = fmaf(w0, rv.x, a0.x); a0.y = fmaf(w0, rv.y, a0.y);
            a0.z = fmaf(w0, rv.z, a0.z); a0.w = fmaf(w0, rv.w, a0.w);
            a1.x = fmaf(w1, rv.x, a1.x); a1.y = fmaf(w1, rv.y, a1.y);
            a1.z = fmaf(w1, rv.z, a1.z); a1.w = fmaf(w1, rv.w, a1.w);
            a2.x = fmaf(w2, rv.x, a2.x); a2.y = fmaf(w2, rv.y, a2.y);
            a2.z = fmaf(w2, rv.z, a2.z); a2.w = fmaf(w2, rv.w, a2.w);
            a3.x = fmaf(w3, rv.x, a3.x); a3.y = fmaf(w3, rv.y, a3.y);
            a3.z = fmaf(w3, rv.z, a3.z); a3.w = fmaf(w3, rv.w, a3.w);
        }
        // partials: [wave][t][256 d]
        *(float4*)&smem[1024 + (w * 4 + 0) * 256 + dl] = a0;
        *(float4*)&smem[1024 + (w * 4 + 1) * 256 + dl] = a1;
        *(float4*)&smem[1024 + (w * 4 + 2) * 256 + dl] = a2;
        *(float4*)&smem[1024 + (w * 4 + 3) * 256 + dl] = a3;
        __syncthreads();
        // Phase 3: 256 threads x 4 outputs: (tt, d=tid)
#pragma unroll
        for (int tt = 0; tt < 4; ++tt) {
            float sum = smem[1024 + (0 * 4 + tt) * 256 + tid] +
                        smem[1024 + (1 * 4 + tt) * 256 + tid] +
                        smem[1024 + (2 * 4 + tt) * 256 + tid] +
                        smem[1024 + (3 * 4 + tt) * 256 + tid];
            out[((size_t)b * T_LEN + tq * 4 + tt) * DIM + hf * 256 + tid] = sum;
        }
    }
}

extern "C" void kernel_launch(void* const* d_in, const int* in_sizes, int n_in,
                              void* d_out, int out_size, void* d_ws, size_t ws_size,
                              hipStream_t stream) {
    const float* topic = (const float*)d_in[0];   // [T,B,D]
    const float* expo  = (const float*)d_in[1];   // [E,B,D]
    const int*   mask  = (const int*)d_in[2];     // [E,B]
    const float* W     = (const float*)d_in[3];   // [H, H+D]
    const float* battn = (const float*)d_in[4];   // [H]
    const float* vsc   = (const float*)d_in[5];   // [1,H]
    float* out = (float*)d_out;                   // new_topic [B,T,D] ++ new_exp [B,E,D]

    float* EPT = (float*)d_ws;                                // [512,512] f32, 1 MB
    __hip_bfloat16* EPE = (__hip_bfloat16*)(EPT + 512 * 512); // [4096,512] bf16, 4 MB
    float* P = (float*)(EPE + (size_t)4096 * 512);            // [B,T,E] f32, 0.5 MB

    gemm_fused_k<<<576, 256, 0, stream>>>(topic, expo, W, battn, EPT, EPE);
    energies_k<<<1024, 256, 0, stream>>>(EPT, EPE, vsc, mask, P);
    epilogue_k<<<768, 256, 0, stream>>>(P, topic, expo, out);
}

// Round 4
// 111.197 us; speedup vs baseline: 2.2612x; 1.0220x over previous
//
#include <hip/hip_runtime.h>
#include <hip/hip_bf16.h>
#include <cstddef>
#include <cstdint>

#define T_LEN 32
#define E_LEN 256
#define BATCH 16
#define DIM 512
#define HID 512
#define WROW 1024  // HID + DIM

#define TWO_LOG2E 2.8853900817779268f  // 2*log2(e)
#define LOG2E 1.4426950408889634f

typedef __attribute__((ext_vector_type(8))) short bf16x8;
typedef __attribute__((ext_vector_type(4))) float f32x4;

__device__ inline bf16x8 cvt8(float4 a, float4 b) {
    union { bf16x8 v; __hip_bfloat16 h[8]; } u;
    u.h[0] = __float2bfloat16(a.x); u.h[1] = __float2bfloat16(a.y);
    u.h[2] = __float2bfloat16(a.z); u.h[3] = __float2bfloat16(a.w);
    u.h[4] = __float2bfloat16(b.x); u.h[5] = __float2bfloat16(b.y);
    u.h[6] = __float2bfloat16(b.z); u.h[7] = __float2bfloat16(b.w);
    return u.v;
}

#define GPAD 8
#define GLDR (64 + GPAD)   // 72 halfwords per LDS row

// ---------------------------------------------------------------------------
// Fused projection GEMM (NT), f32 in -> bf16 MFMA -> exp2 -> out.
// Tile 64x64, BK=64, 256 threads, register-prefetched global loads,
// LDS double-buffered: one __syncthreads per K-step.
// ---------------------------------------------------------------------------
__global__ __launch_bounds__(256) void gemm_fused_k(
    const float* __restrict__ topic, const float* __restrict__ expo,
    const float* __restrict__ W, const float* __restrict__ battn,
    float* __restrict__ EPT, __hip_bfloat16* __restrict__ EPE) {
    __shared__ __align__(16) __hip_bfloat16 As[2][64 * GLDR];
    __shared__ __align__(16) __hip_bfloat16 Bs[2][64 * GLDR];
    const int tid = threadIdx.x;
    const int by = blockIdx.x >> 3;       // 0..71
    const int n0 = (blockIdx.x & 7) * 64;
    const float* A; const float* Wp; int m0;
    const bool isT = (by < 8);
    if (isT) { A = topic; Wp = W;       m0 = by * 64; }
    else     { A = expo;  Wp = W + DIM; m0 = (by - 8) * 64; }
    const int w = tid >> 6;
    const int lane = tid & 63;
    const int l15 = lane & 15;
    const int g = lane >> 4;
    const int srow = tid >> 2;   // 0..63
    const int sc = tid & 3;      // halfword chunks at sc*8 and sc*8+32

    f32x4 acc[4];
    const f32x4 z = {0.f, 0.f, 0.f, 0.f};
#pragma unroll
    for (int nt = 0; nt < 4; ++nt) acc[nt] = z;

    const float* ga = A + (size_t)(m0 + srow) * 512 + sc * 8;
    const float* gb = Wp + (size_t)(n0 + srow) * WROW + sc * 8;

    float4 a0 = *(const float4*)(ga);
    float4 a1 = *(const float4*)(ga + 4);
    float4 a2 = *(const float4*)(ga + 32);
    float4 a3 = *(const float4*)(ga + 36);
    float4 b0 = *(const float4*)(gb);
    float4 b1 = *(const float4*)(gb + 4);
    float4 b2 = *(const float4*)(gb + 32);
    float4 b3 = *(const float4*)(gb + 36);

    for (int kk = 0; kk < 8; ++kk) {
        const int cur = kk & 1;
        bf16x8 av0 = cvt8(a0, a1), av1 = cvt8(a2, a3);
        bf16x8 bv0 = cvt8(b0, b1), bv1 = cvt8(b2, b3);
        if (kk < 7) {  // prefetch next K-chunk while this one computes
            ga += 64; gb += 64;
            a0 = *(const float4*)(ga);
            a1 = *(const float4*)(ga + 4);
            a2 = *(const float4*)(ga + 32);
            a3 = *(const float4*)(ga + 36);
            b0 = *(const float4*)(gb);
            b1 = *(const float4*)(gb + 4);
            b2 = *(const float4*)(gb + 32);
            b3 = *(const float4*)(gb + 36);
        }
        *(bf16x8*)&As[cur][srow * GLDR + sc * 8] = av0;
        *(bf16x8*)&As[cur][srow * GLDR + sc * 8 + 32] = av1;
        *(bf16x8*)&Bs[cur][srow * GLDR + sc * 8] = bv0;
        *(bf16x8*)&Bs[cur][srow * GLDR + sc * 8 + 32] = bv1;
        __syncthreads();
#pragma unroll
        for (int s = 0; s < 2; ++s) {
            bf16x8 af = *(const bf16x8*)&As[cur][(w * 16 + l15) * GLDR + (s * 4 + g) * 8];
#pragma unroll
            for (int nt = 0; nt < 4; ++nt) {
                bf16x8 bf = *(const bf16x8*)&Bs[cur][(nt * 16 + l15) * GLDR + (s * 4 + g) * 8];
                acc[nt] = __builtin_amdgcn_mfma_f32_16x16x32_bf16(af, bf, acc[nt], 0, 0, 0);
            }
        }
    }
    if (isT) {
#pragma unroll
        for (int nt = 0; nt < 4; ++nt) {
            int n = n0 + nt * 16 + l15;
            float bv = battn[n];
#pragma unroll
            for (int r = 0; r < 4; ++r) {
                int m = m0 + w * 16 + g * 4 + r;
                EPT[(size_t)m * 512 + n] =
                    __builtin_amdgcn_exp2f((acc[nt][r] + bv) * TWO_LOG2E);
            }
        }
    } else {
#pragma unroll
        for (int nt = 0; nt < 4; ++nt) {
            int n = n0 + nt * 16 + l15;
#pragma unroll
            for (int r = 0; r < 4; ++r) {
                int m = m0 + w * 16 + g * 4 + r;
                EPE[(size_t)m * 512 + n] = __float2bfloat16(
                    __builtin_amdgcn_exp2f(acc[nt][r] * TWO_LOG2E));
            }
        }
    }
}

// ---------------------------------------------------------------------------
// Energies -> P[b,t,e] and PT[b,e,t] = exp(energy - const); masked -> 1e-30.
// 4-way reciprocal combining (validated): 15 VALU + 1 rcp per quad.
// PACKED butterfly reduction: res = (bit?keepQ:keepP) + shfl_xor(bit?P:Q, m)
// merges 2 accumulators per shuffle -> 10 shuffles/ei instead of 36
// (energies was DS-pipe-bound: R3's VALU cut was null). Final mapping
// t = lane&7 — identical to old sel/uA/uB path.
// Wave: 4 e's x 8 t's; block = (b, 8 t's, 16 e's); grid 1024.
// ---------------------------------------------------------------------------
__global__ __launch_bounds__(256) void energies_k(
    const float* __restrict__ EPT, const __hip_bfloat16* __restrict__ EPE,
    const float* __restrict__ v, const int* __restrict__ mask,
    float* __restrict__ P, float* __restrict__ PT) {
    const int u = blockIdx.x;
    const int b = u & 15;
    const int tg = (u >> 4) & 3;   // t = tg*8 + i
    const int ech = u >> 6;        // e base = ech*16
    const int tid = threadIdx.x;
    const int lane = tid & 63;
    const int w = tid >> 6;
    const int h0 = lane * 8;
    const int e0 = ech * 16 + w * 4;
    const bool o1 = (lane & 1) != 0;
    const bool o2 = (lane & 2) != 0;
    const bool o4 = (lane & 4) != 0;

    int mk[4];
#pragma unroll
    for (int ei = 0; ei < 4; ++ei) mk[ei] = mask[(e0 + ei) * BATCH + b];

    float sv[8], sv2[4], spt[8][8];
    {
        float4 v0 = *(const float4*)(v + h0);
        float4 v1 = *(const float4*)(v + h0 + 4);
        sv[0] = -2.f * v0.x; sv[1] = -2.f * v0.y; sv[2] = -2.f * v0.z; sv[3] = -2.f * v0.w;
        sv[4] = -2.f * v1.x; sv[5] = -2.f * v1.y; sv[6] = -2.f * v1.z; sv[7] = -2.f * v1.w;
        sv2[0] = sv[0] + sv[1]; sv2[1] = sv[2] + sv[3];
        sv2[2] = sv[4] + sv[5]; sv2[3] = sv[6] + sv[7];
#pragma unroll
        for (int i = 0; i < 8; ++i) {
            const float* p = EPT + ((size_t)((tg * 8 + i) * BATCH + b)) * HID + h0;
            float4 p0 = *(const float4*)(p);
            float4 p1 = *(const float4*)(p + 4);
            spt[i][0] = p0.x; spt[i][1] = p0.y; spt[i][2] = p0.z; spt[i][3] = p0.w;
            spt[i][4] = p1.x; spt[i][5] = p1.y; spt[i][6] = p1.z; spt[i][7] = p1.w;
        }
    }
#pragma unroll
    for (int ei = 0; ei < 4; ++ei) {
        const int e = e0 + ei;
        if (mk[ei] != 0) {  // wave-uniform skip
            if (lane < 8) {
                P[((size_t)b * T_LEN + tg * 8 + lane) * E_LEN + e] = 1e-30f;
                PT[((size_t)b * E_LEN + e) * T_LEN + tg * 8 + lane] = 1e-30f;
            }
            continue;
        }
        union { bf16x8 v8; __hip_bfloat16 h[8]; } pv;
        pv.v8 = *(const bf16x8*)(EPE + ((size_t)(e * BATCH + b)) * HID + h0);
        float pr[8];
#pragma unroll
        for (int j = 0; j < 8; ++j) pr[j] = __bfloat162float(pv.h[j]);
        float a[8] = {0.f, 0.f, 0.f, 0.f, 0.f, 0.f, 0.f, 0.f};
#pragma unroll
        for (int i = 0; i < 8; ++i) {
#pragma unroll
            for (int jq = 0; jq < 2; ++jq) {
                const int j0 = jq * 4;
                float a0 = spt[i][j0 + 0] * pr[j0 + 0];
                float a1 = spt[i][j0 + 1] * pr[j0 + 1];
                float a2 = spt[i][j0 + 2] * pr[j0 + 2];
                float a3 = spt[i][j0 + 3] * pr[j0 + 3];
                float u0 = a0 + 1.0f;
                float u2 = a2 + 1.0f;
                float d01 = fmaf(a1, u0, u0);           // (1+a0)(1+a1)
                float d23 = fmaf(a3, u2, u2);           // (1+a2)(1+a3)
                float n01 = fmaf(sv[j0 + 0], a1, fmaf(sv[j0 + 1], a0, sv2[jq * 2 + 0]));
                float n23 = fmaf(sv[j0 + 2], a3, fmaf(sv[j0 + 3], a2, sv2[jq * 2 + 1]));
                float nn = fmaf(n01, d23, n23 * d01);
                float dd = d01 * d23;
                a[i] = fmaf(nn, __builtin_amdgcn_rcpf(dd), a[i]);
            }
        }
        // Packed butterfly: level 1 (xor 1) — 8 accs -> 4, 4 shuffles
        float s, b0, b1, b2, b3, d0, d1, f;
        s = __shfl_xor(o1 ? a[0] : a[1], 1); b0 = (o1 ? a[1] : a[0]) + s;
        s = __shfl_xor(o1 ? a[2] : a[3], 1); b1 = (o1 ? a[3] : a[2]) + s;
        s = __shfl_xor(o1 ? a[4] : a[5], 1); b2 = (o1 ? a[5] : a[4]) + s;
        s = __shfl_xor(o1 ? a[6] : a[7], 1); b3 = (o1 ? a[7] : a[6]) + s;
        // level 2 (xor 2) — 4 -> 2
        s = __shfl_xor(o2 ? b0 : b1, 2); d0 = (o2 ? b1 : b0) + s;
        s = __shfl_xor(o2 ? b2 : b3, 2); d1 = (o2 ? b3 : b2) + s;
        // level 3 (xor 4) — 2 -> 1; lane now holds t = lane&7 partial
        s = __shfl_xor(o4 ? d0 : d1, 4); f = (o4 ? d1 : d0) + s;
        // levels 4-6: plain adds complete the 64-lane sum
        f += __shfl_xor(f, 8);
        f += __shfl_xor(f, 16);
        f += __shfl_xor(f, 32);
        if (lane < 8) {
            float pe = __builtin_amdgcn_exp2f(f * LOG2E);
            P[((size_t)b * T_LEN + tg * 8 + lane) * E_LEN + e] = pe;
            PT[((size_t)b * E_LEN + e) * T_LEN + tg * 8 + lane] = pe;
        }
    }
}

// ---------------------------------------------------------------------------
// Fused epilogue on P/PT, 768 blocks.
// blocks [0,512): new_exp, block=(b, e-chunk of 16, d-half). Softmax reads
//   the coalesced PT row; weights staged in LDS [e_local][32]; main loop
//   reads per-t-quad b128 broadcasts (replaces 128 shuffles/thread).
// blocks [512,768): new_topic, block=(b, t-quad, d-half): weights stored
//   [e][4] so phase-2 reads ONE b128 broadcast per e (was 4 scalar reads).
// ---------------------------------------------------------------------------
__global__ __launch_bounds__(256) void epilogue_k(
    const float* __restrict__ P, const float* __restrict__ PT,
    const float* __restrict__ topic,
    const float* __restrict__ expo, float* __restrict__ out) {
    __shared__ __align__(16) float smem[5120];
    const int tid = threadIdx.x;
    const int lane = tid & 63;
    const int w = tid >> 6;
    if (blockIdx.x < 512) {
        // ---- new_exp ----
        const int b = blockIdx.x >> 5;
        const int ech = (blockIdx.x >> 1) & 15;
        const int hf = blockIdx.x & 1;
        const int e0 = ech * 16 + w * 4;
        // weights: wsm[e_local][32], e_local = w*4+ei
#pragma unroll
        for (int ei = 0; ei < 4; ++ei) {
            const int e = e0 + ei;
            float x = 0.f;
            if (lane < T_LEN)
                x = PT[((size_t)b * E_LEN + e) * T_LEN + lane];  // coalesced row
            float s = x;
#pragma unroll
            for (int off = 32; off; off >>= 1) s += __shfl_xor(s, off);
            float wv = x * __builtin_amdgcn_rcpf(s);
            if (lane < T_LEN) smem[(w * 4 + ei) * 32 + lane] = wv;
        }
        __syncthreads();
        const int d0 = hf * 256 + lane * 4;
        float4 acc[4];
#pragma unroll
        for (int ei = 0; ei < 4; ++ei) acc[ei] = {0.f, 0.f, 0.f, 0.f};
#pragma unroll 2
        for (int tq = 0; tq < 8; ++tq) {
            float wqa[4][4];
#pragma unroll
            for (int ei = 0; ei < 4; ++ei) {
                float4 q = *(const float4*)&smem[(w * 4 + ei) * 32 + tq * 4];  // broadcast
                wqa[ei][0] = q.x; wqa[ei][1] = q.y; wqa[ei][2] = q.z; wqa[ei][3] = q.w;
            }
#pragma unroll
            for (int tt = 0; tt < 4; ++tt) {
                const int t = tq * 4 + tt;
                float4 r = *(const float4*)(topic + ((size_t)t * BATCH + b) * DIM + d0);
#pragma unroll
                for (int ei = 0; ei < 4; ++ei) {
                    acc[ei].x = fmaf(wqa[ei][tt], r.x, acc[ei].x);
                    acc[ei].y = fmaf(wqa[ei][tt], r.y, acc[ei].y);
                    acc[ei].z = fmaf(wqa[ei][tt], r.z, acc[ei].z);
                    acc[ei].w = fmaf(wqa[ei][tt], r.w, acc[ei].w);
                }
            }
        }
#pragma unroll
        for (int ei = 0; ei < 4; ++ei) {
            float* o = out + (size_t)BATCH * T_LEN * DIM +
                       ((size_t)b * E_LEN + e0 + ei) * DIM + d0;
            *(float4*)o = acc[ei];
        }
    } else {
        // ---- new_topic (t-quad) ----
        const int q = blockIdx.x - 512;   // [0,256)
        const int b = q >> 4;             // 16 b
        const int tq = (q >> 1) & 7;      // t-quad: t = tq*4 + {0..3}
        const int hf = q & 1;             // d-half
        // Phase 1: wave w computes softmax weights for t = tq*4 + w,
        // stored transposed [e][4] (one-time 32-way-conflict store, accepted).
        {
            const int bt = b * T_LEN + tq * 4 + w;
            float4 xv = *(const float4*)&P[(size_t)bt * E_LEN + lane * 4];
            float s = xv.x + xv.y + xv.z + xv.w;
#pragma unroll
            for (int off = 32; off; off >>= 1) s += __shfl_xor(s, off);
            float inv = __builtin_amdgcn_rcpf(s);
            smem[(lane * 4 + 0) * 4 + w] = xv.x * inv;
            smem[(lane * 4 + 1) * 4 + w] = xv.y * inv;
            smem[(lane * 4 + 2) * 4 + w] = xv.z * inv;
            smem[(lane * 4 + 3) * 4 + w] = xv.w * inv;
        }
        __syncthreads();
        // Phase 2: wave w handles e in [w*64, w*64+64); lane owns 4 d's;
        // ONE b128 weight broadcast per e (was 4 scalar LDS reads).
        const int dl = lane * 4;
        const int dglob = hf * 256 + dl;
        float4 a0 = {0.f, 0.f, 0.f, 0.f};
        float4 a1 = {0.f, 0.f, 0.f, 0.f};
        float4 a2 = {0.f, 0.f, 0.f, 0.f};
        float4 a3 = {0.f, 0.f, 0.f, 0.f};
        const float* base = expo + (size_t)b * DIM + dglob;
        for (int ee = 0; ee < 64; ++ee) {
            const int e = w * 64 + ee;
            float4 rv = *(const float4*)(base + (size_t)e * BATCH * DIM);
            float4 wq = *(const float4*)&smem[e * 4];  // uniform addr -> broadcast
            a0.x = fmaf(wq.x, rv.x, a0.x); a0.y = fmaf(wq.x, rv.y, a0.y);
            a0.z = fmaf(wq.x, rv.z, a0.z); a0.w = fmaf(wq.x, rv.w, a0.w);
            a1.x = fmaf(wq.y, rv.x, a1.x); a1.y = fmaf(wq.y, rv.y, a1.y);
            a1.z = fmaf(wq.y, rv.z, a1.z); a1.w = fmaf(wq.y, rv.w, a1.w);
            a2.x = fmaf(wq.z, rv.x, a2.x); a2.y = fmaf(wq.z, rv.y, a2.y);
            a2.z = fmaf(wq.z, rv.z, a2.z); a2.w = fmaf(wq.z, rv.w, a2.w);
            a3.x = fmaf(wq.w, rv.x, a3.x); a3.y = fmaf(wq.w, rv.y, a3.y);
            a3.z = fmaf(wq.w, rv.z, a3.z); a3.w = fmaf(wq.w, rv.w, a3.w);
        }
        // partials: [wave][t][256 d]
        *(float4*)&smem[1024 + (w * 4 + 0) * 256 + dl] = a0;
        *(float4*)&smem[1024 + (w * 4 + 1) * 256 + dl] = a1;
        *(float4*)&smem[1024 + (w * 4 + 2) * 256 + dl] = a2;
        *(float4*)&smem[1024 + (w * 4 + 3) * 256 + dl] = a3;
        __syncthreads();
        // Phase 3: 256 threads x 4 outputs: (tt, d=tid)
#pragma unroll
        for (int tt = 0; tt < 4; ++tt) {
            float sum = smem[1024 + (0 * 4 + tt) * 256 + tid] +
                        smem[1024 + (1 * 4 + tt) * 256 + tid] +
                        smem[1024 + (2 * 4 + tt) * 256 + tid] +
                        smem[1024 + (3 * 4 + tt) * 256 + tid];
            out[((size_t)b * T_LEN + tq * 4 + tt) * DIM + hf * 256 + tid] = sum;
        }
    }
}

extern "C" void kernel_launch(void* const* d_in, const int* in_sizes, int n_in,
                              void* d_out, int out_size, void* d_ws, size_t ws_size,
                              hipStream_t stream) {
    const float* topic = (const float*)d_in[0];   // [T,B,D]
    const float* expo  = (const float*)d_in[1];   // [E,B,D]
    const int*   mask  = (const int*)d_in[2];     // [E,B]
    const float* W     = (const float*)d_in[3];   // [H, H+D]
    const float* battn = (const float*)d_in[4];   // [H]
    const float* vsc   = (const float*)d_in[5];   // [1,H]
    float* out = (float*)d_out;                   // new_topic [B,T,D] ++ new_exp [B,E,D]

    float* EPT = (float*)d_ws;                                // [512,512] f32, 1 MB
    __hip_bfloat16* EPE = (__hip_bfloat16*)(EPT + 512 * 512); // [4096,512] bf16, 4 MB
    float* P  = (float*)(EPE + (size_t)4096 * 512);           // [B,T,E] f32, 0.5 MB
    float* PT = P + (size_t)BATCH * T_LEN * E_LEN;            // [B,E,T] f32, 0.5 MB

    gemm_fused_k<<<576, 256, 0, stream>>>(topic, expo, W, battn, EPT, EPE);
    energies_k<<<1024, 256, 0, stream>>>(EPT, EPE, vsc, mask, P, PT);
    epilogue_k<<<768, 256, 0, stream>>>(P, PT, topic, expo, out);
}